// Round 1
// 433.803 us; speedup vs baseline: 1.0720x; 1.0720x over previous
//
#include <hip/hip_runtime.h>

#define D_DIM 764
#define DP    768
#define BM    128
#define BN    128
#define BK    64

typedef __attribute__((ext_vector_type(8))) short bf16x8;
typedef __attribute__((ext_vector_type(8))) unsigned short u16x8;
typedef __attribute__((ext_vector_type(4))) float f32x4;

typedef __attribute__((address_space(3))) char lds_char;
typedef __attribute__((address_space(1))) const char g_char;

__device__ inline unsigned short f2bf(float f) {
    union { float f; unsigned u; } v; v.f = f;
    unsigned r = v.u + 0x7FFFu + ((v.u >> 16) & 1u);  // RNE
    return (unsigned short)(r >> 16);
}

// Mask (k < n), cast to bf16, pad to DP x DP. Layout: Wb[n][k] (BT form, K-contiguous).
__global__ void prep_w(const float* __restrict__ W, unsigned short* __restrict__ Wb) {
    int idx = blockIdx.x * blockDim.x + threadIdx.x;   // 0 .. DP*DP-1
    int n = idx / DP, k = idx - n * DP;
    float v = 0.0f;
    if (n < D_DIM && k < n) v = W[n * D_DIM + k];
    Wb[idx] = f2bf(v);
}

// 128x128 tile, BK=64, 8 waves (4m x 2n, 32x64 each), 16x16x32 bf16 MFMA.
// v2: double-buffered LDS + issue-early/write-late staging. Per iteration:
//   LOAD_A(t+1)->regs ; STAGE_B(t+1) global_load_lds ; COMPUTE(t) ; WRITE_A(t+1) ; barrier
// so HBM/L2 latency of tile t+1 hides under the MFMAs of tile t.
// 64 KB LDS -> 2 blocks/CU = 16 waves; __launch_bounds__(512,4) caps VGPR at 128.
// Swizzle: chunk position c of row r holds global chunk (c ^ (r&7)) -> valid
// global_load_lds (uniform base + lane*16) AND 2-way-max ds_read_b128 banking.
__global__ __launch_bounds__(512, 4) void fvsbn_gemm(
    const float* __restrict__ X,          // [65536, 764] fp32
    const unsigned short* __restrict__ Wb,// [768, 768] bf16 masked (BT layout)
    const float* __restrict__ bias,       // [764] fp32
    float* __restrict__ out)              // [65536, 764] fp32
{
    __shared__ __align__(16) unsigned short As[2][BM * BK]; // 2 x 16 KB
    __shared__ __align__(16) unsigned short Bs[2][BN * BK]; // 2 x 16 KB

    const int tid  = threadIdx.x;
    const int lane = tid & 63;
    const int wid  = tid >> 6;        // 0..7
    const int wm   = wid & 3;         // 32-row m-slice
    const int wn   = wid >> 2;        // 64-col n-slice
    const int quad = lane >> 4;
    const int l16  = lane & 15;

    // XCD-aware swizzle: 512 m-tiles x 6 n-tiles, contiguous m per XCD.
    const int bid = blockIdx.x;       // 0..3071
    const int xcd = bid & 7;
    const int j   = bid >> 3;         // 0..383
    const int nt  = j % 6;
    const int jm  = j / 6;            // 0..63
    const int mt  = jm * 8 + xcd;     // 0..511
    const int m0  = mt * BM;
    const int n0  = nt * BN;

    // Triangular skip: cols [n0, n0+127] need k <= n0+126.
    const int num_k = (n0 + BN) / BK;  // 2,4,6,8,10,12

    // ---- staging descriptors (K-invariant; add k0 at issue) ----
    // B: 2 chunk-groups of 64 per wave (1024 chunks total).
    const unsigned short* bsrc[2];
#pragma unroll
    for (int jj = 0; jj < 2; ++jj) {
        const int c  = (wid * 2 + jj) * 64 + lane;   // 0..1023
        const int r  = c >> 3;
        const int cc = c & 7;
        const int g  = cc ^ (r & 7);
        bsrc[jj] = Wb + (size_t)(n0 + r) * DP + g * 8;
    }
    // A: 2 positions per thread (1024 total).
    const float* asrc[2];
    int adst[2], hilim[2];
#pragma unroll
    for (int i = 0; i < 2; ++i) {
        const int p  = tid + i * 512;                // 0..1023
        const int r  = p >> 3;
        const int cc = p & 7;
        const int g  = cc ^ (r & 7);
        asrc[i]  = X + (size_t)(m0 + r) * D_DIM + g * 8;
        adst[i]  = r * BK + cc * 8;
        hilim[i] = D_DIM - 8 - g * 8;  // hi float4 valid iff k0 <= hilim[i]
    }

    f32x4 acc[2][4];
#pragma unroll
    for (int mi = 0; mi < 2; ++mi)
#pragma unroll
        for (int ni = 0; ni < 4; ++ni) acc[mi][ni] = (f32x4){0.f, 0.f, 0.f, 0.f};

    float4 xlo[2], xhi[2];

#define LOAD_A(k0s)                                                         \
    _Pragma("unroll")                                                       \
    for (int i = 0; i < 2; ++i) {                                           \
        const float* xp = asrc[i] + (k0s);                                  \
        xlo[i] = *(const float4*)xp;                                        \
        xhi[i] = ((k0s) <= hilim[i]) ? *(const float4*)(xp + 4)             \
                                     : make_float4(0.f, 0.f, 0.f, 0.f);     \
    }

#define STAGE_B(buf, k0s)                                                   \
    _Pragma("unroll")                                                       \
    for (int jj = 0; jj < 2; ++jj) {                                        \
        __builtin_amdgcn_global_load_lds(                                   \
            (g_char*)(bsrc[jj] + (k0s)),                                    \
            (lds_char*)((char*)&Bs[buf][0] + ((wid * 2 + jj) * 64) * 16),   \
            16, 0, 0);                                                      \
    }

#define WRITE_A(buf)                                                        \
    _Pragma("unroll")                                                       \
    for (int i = 0; i < 2; ++i) {                                           \
        u16x8 pk;                                                           \
        pk[0] = f2bf(xlo[i].x); pk[1] = f2bf(xlo[i].y);                     \
        pk[2] = f2bf(xlo[i].z); pk[3] = f2bf(xlo[i].w);                     \
        pk[4] = f2bf(xhi[i].x); pk[5] = f2bf(xhi[i].y);                     \
        pk[6] = f2bf(xhi[i].z); pk[7] = f2bf(xhi[i].w);                     \
        *(u16x8*)&As[buf][adst[i]] = pk;                                    \
    }

#define COMPUTE(buf)                                                        \
    _Pragma("unroll")                                                       \
    for (int s = 0; s < 2; ++s) {                                           \
        bf16x8 af[2], bfr[4];                                               \
        _Pragma("unroll")                                                   \
        for (int mi = 0; mi < 2; ++mi) {                                    \
            const int r = wm * 32 + mi * 16 + l16;                          \
            const int g = s * 4 + quad;                                     \
            af[mi] = *(const bf16x8*)&As[buf][r * BK + (g ^ (r & 7)) * 8];  \
        }                                                                   \
        _Pragma("unroll")                                                   \
        for (int ni = 0; ni < 4; ++ni) {                                    \
            const int r = wn * 64 + ni * 16 + l16;                          \
            const int g = s * 4 + quad;                                     \
            bfr[ni] = *(const bf16x8*)&Bs[buf][r * BK + (g ^ (r & 7)) * 8]; \
        }                                                                   \
        _Pragma("unroll")                                                   \
        for (int mi = 0; mi < 2; ++mi)                                      \
            _Pragma("unroll")                                               \
            for (int ni = 0; ni < 4; ++ni)                                  \
                acc[mi][ni] = __builtin_amdgcn_mfma_f32_16x16x32_bf16(      \
                    af[mi], bfr[ni], acc[mi][ni], 0, 0, 0);                 \
    }

    // ---- prologue: stage tile 0 ----
    LOAD_A(0);
    STAGE_B(0, 0);
    WRITE_A(0);
    __syncthreads();

    int cur = 0;
    for (int kk = 0; kk < num_k; ++kk) {
        const int nxt  = cur ^ 1;
        const bool more = (kk + 1 < num_k);
        if (more) {
            const int k0n = (kk + 1) * BK;
            LOAD_A(k0n);          // X -> regs, consumed after COMPUTE
            STAGE_B(nxt, k0n);    // async global->LDS, drained at the barrier
        }
        COMPUTE(cur);
        if (more) WRITE_A(nxt);   // waits A-load vmcnt, packs, ds_write
        __syncthreads();
        cur = nxt;
    }

    // ---- epilogue: + bias, store fp32 (col bound-checked vs 764) ----
#pragma unroll
    for (int ni = 0; ni < 4; ++ni) {
        const int col = n0 + wn * 64 + ni * 16 + l16;
        if (col < D_DIM) {
            const float bv = bias[col];
#pragma unroll
            for (int mi = 0; mi < 2; ++mi) {
                const int row = m0 + wm * 32 + mi * 16 + quad * 4;
#pragma unroll
                for (int r = 0; r < 4; ++r)
                    out[(size_t)(row + r) * D_DIM + col] = acc[mi][ni][r] + bv;
            }
        }
    }
#undef LOAD_A
#undef STAGE_B
#undef WRITE_A
#undef COMPUTE
}

extern "C" void kernel_launch(void* const* d_in, const int* in_sizes, int n_in,
                              void* d_out, int out_size, void* d_ws, size_t ws_size,
                              hipStream_t stream) {
    const float* X    = (const float*)d_in[0];
    const float* W    = (const float*)d_in[1];
    const float* bias = (const float*)d_in[2];
    float* out        = (float*)d_out;
    unsigned short* Wb = (unsigned short*)d_ws;  // DP*DP bf16 = 1.18 MB

    prep_w<<<(DP * DP) / 256, 256, 0, stream>>>(W, Wb);
    fvsbn_gemm<<<(65536 / BM) * (DP / BN), 512, 0, stream>>>(X, Wb, bias, out);
}